// Round 1
// baseline (338.660 us; speedup 1.0000x reference)
//
#include <hip/hip_runtime.h>

typedef float        f32x4  __attribute__((ext_vector_type(4)));
typedef unsigned int u32x4  __attribute__((ext_vector_type(4)));
typedef unsigned int u32x2  __attribute__((ext_vector_type(2)));
typedef __bf16       bf16x8 __attribute__((ext_vector_type(8)));

#define DEVFN static __device__ __forceinline__

DEVFN unsigned short f2bf(float f){
  unsigned u = __builtin_bit_cast(unsigned, f);
  u += 0x7FFFu + ((u >> 16) & 1u);            // RNE
  return (unsigned short)(u >> 16);
}
DEVFN unsigned pack2(float a, float b){
  return (unsigned)f2bf(a) | ((unsigned)f2bf(b) << 16);
}
DEVFN bf16x8 as_bf(u32x4 v){ union{u32x4 u; bf16x8 b;} x; x.u=v; return x.b; }

DEVFN void gload16(const char* src, char* lds){
  __builtin_amdgcn_global_load_lds(
      (__attribute__((address_space(1))) void*)src,
      (__attribute__((address_space(3))) void*)lds, 16, 0, 0);
}

constexpr int BB = 16, NQ = 2048, NK = 2048, F = 512, D = 256, FV = 512;

// ---------------- projection + row l2norm ----------------
// Y[m][n] = l2norm_rows( X[m][:] . W[n][:] ), 32 rows/block.
// TR=true: write Y transposed per-batch: Yt[b][n][m%2048].
template<int KD, int ND, bool TR>
__global__ __launch_bounds__(256,2) void proj_kernel(const float* __restrict__ X,
                                                     const float* __restrict__ W,
                                                     unsigned short* __restrict__ Y)
{
  constexpr int NW = ND/4;
  constexpr int AF = TR ? 8 : 2;
  constexpr int BF = TR ? 2 : NW/16;
  __shared__ __align__(16) char xsm[32*80];
  __shared__ __align__(16) char wsm[ND*80];
  __shared__ float wsum[4][32];
  const int tid = threadIdx.x;
  const int lane = tid & 63;
  const int wid = tid >> 6;
  const int q16 = lane & 15;
  const int g = lane >> 4;
  const int row0 = blockIdx.x * 32;
  const int rX = tid >> 3, cX = (tid & 7) * 4;

  f32x4 z4 = {0.f,0.f,0.f,0.f};
  f32x4 acc[AF][BF];
  #pragma unroll
  for (int i=0;i<AF;i++){
    #pragma unroll
    for (int j=0;j<BF;j++) acc[i][j] = z4;
  }

  for (int k0 = 0; k0 < KD; k0 += 32){
    { // X tile [32][32] -> bf16 LDS, stride 80B (pad kills conflicts)
      f32x4 v = *(const f32x4*)(X + (size_t)(row0+rX)*KD + k0 + cX);
      u32x2 p; p[0]=pack2(v[0],v[1]); p[1]=pack2(v[2],v[3]);
      *(u32x2*)(xsm + rX*80 + cX*2) = p;
    }
    #pragma unroll
    for (int j=0;j<ND/32;j++){ // W tile [ND][32]
      int r = j*32 + rX;
      f32x4 v = *(const f32x4*)(W + (size_t)r*KD + k0 + cX);
      u32x2 p; p[0]=pack2(v[0],v[1]); p[1]=pack2(v[2],v[3]);
      *(u32x2*)(wsm + r*80 + cX*2) = p;
    }
    __syncthreads();
    if constexpr (!TR){
      bf16x8 a[2], bb[BF];
      #pragma unroll
      for (int mi=0;mi<2;mi++)  a[mi]  = as_bf(*(const u32x4*)(xsm + (16*mi+q16)*80 + g*16));
      #pragma unroll
      for (int ni=0;ni<BF;ni++) bb[ni] = as_bf(*(const u32x4*)(wsm + (wid*NW + 16*ni + q16)*80 + g*16));
      #pragma unroll
      for (int mi=0;mi<2;mi++){
        #pragma unroll
        for (int ni=0;ni<BF;ni++)
          acc[mi][ni] = __builtin_amdgcn_mfma_f32_16x16x32_bf16(a[mi], bb[ni], acc[mi][ni], 0,0,0);
      }
    } else {
      bf16x8 a[8], bb[2];
      #pragma unroll
      for (int ai=0;ai<8;ai++) a[ai] = as_bf(*(const u32x4*)(wsm + (wid*NW + 16*ai + q16)*80 + g*16));
      #pragma unroll
      for (int ci=0;ci<2;ci++) bb[ci] = as_bf(*(const u32x4*)(xsm + (16*ci+q16)*80 + g*16));
      #pragma unroll
      for (int ai=0;ai<8;ai++){
        #pragma unroll
        for (int ci=0;ci<2;ci++)
          acc[ai][ci] = __builtin_amdgcn_mfma_f32_16x16x32_bf16(a[ai], bb[ci], acc[ai][ci], 0,0,0);
      }
    }
    __syncthreads();
  }

  if constexpr (!TR){
    float part[2][4];
    #pragma unroll
    for (int mi=0;mi<2;mi++){
      #pragma unroll
      for (int r=0;r<4;r++){
        float s=0.f;
        #pragma unroll
        for (int ni=0;ni<BF;ni++){ float v=acc[mi][ni][r]; s += v*v; }
        part[mi][r]=s;
      }
    }
    #pragma unroll
    for (int m=1;m<16;m<<=1){
      #pragma unroll
      for (int mi=0;mi<2;mi++){
        #pragma unroll
        for (int r=0;r<4;r++) part[mi][r] += __shfl_xor(part[mi][r], m);
      }
    }
    if (q16 == 0){
      #pragma unroll
      for (int mi=0;mi<2;mi++){
        #pragma unroll
        for (int r=0;r<4;r++) wsum[wid][16*mi + 4*g + r] = part[mi][r];
      }
    }
    __syncthreads();
    #pragma unroll
    for (int mi=0;mi<2;mi++){
      #pragma unroll
      for (int r=0;r<4;r++){
        int m = 16*mi + 4*g + r;
        float tot = wsum[0][m]+wsum[1][m]+wsum[2][m]+wsum[3][m];
        float inv = 1.f / fmaxf(sqrtf(tot), 1e-12f);
        #pragma unroll
        for (int ni=0;ni<BF;ni++){
          int col = wid*NW + 16*ni + q16;
          Y[(size_t)(row0+m)*ND + col] = f2bf(acc[mi][ni][r]*inv);
        }
      }
    }
  } else {
    float pp[2];
    #pragma unroll
    for (int ci=0;ci<2;ci++){
      float s=0.f;
      #pragma unroll
      for (int ai=0;ai<8;ai++){
        #pragma unroll
        for (int r=0;r<4;r++){ float v=acc[ai][ci][r]; s += v*v; }
      }
      pp[ci]=s;
    }
    #pragma unroll
    for (int ci=0;ci<2;ci++){
      pp[ci] += __shfl_xor(pp[ci],16);
      pp[ci] += __shfl_xor(pp[ci],32);
    }
    if (lane < 16){ wsum[wid][lane] = pp[0]; wsum[wid][16+lane] = pp[1]; }
    __syncthreads();
    #pragma unroll
    for (int ci=0;ci<2;ci++){
      int m = 16*ci + q16;
      float tot = wsum[0][m]+wsum[1][m]+wsum[2][m]+wsum[3][m];
      float inv = 1.f / fmaxf(sqrtf(tot), 1e-12f);
      int grow = row0 + m;
      int b = grow >> 11;
      int kv = grow & 2047;
      #pragma unroll
      for (int ai=0;ai<8;ai++){
        #pragma unroll
        for (int r=0;r<4;r++){
          int n = wid*NW + 16*ai + 4*g + r;
          Y[((size_t)b*FV + n)*NK + kv] = f2bf(acc[ai][ci][r]*inv);
        }
      }
    }
  }
}

// ---------------- fused attention ----------------
// Per block: 64 q rows (4 waves x 16), loop kv in tiles of 32.
// S^T = mfma(K, Q); fixed softmax max (cosine logits <= 1/16); O^T = mfma(Vt, P^T).
__global__ __launch_bounds__(256,2) void attn_kernel(const float* __restrict__ query,
    const unsigned short* __restrict__ wq, const unsigned short* __restrict__ wk,
    const unsigned short* __restrict__ wvt, float* __restrict__ out)
{
  __shared__ __align__(16) char smem[53248];     // 16K wk | 32K wv | 4K p
  char* const wk_lds = smem;
  char* const wv_lds = smem + 16384;
  char* const p_lds  = smem + 49152;
  const int tid = threadIdx.x, lane = tid & 63, wid = tid >> 6;
  const int q16 = lane & 15, g = lane >> 4;
  const int blk = blockIdx.x;
  const int b = blk >> 5;
  const int qblk = blk & 31;
  const int q0w = qblk*64 + wid*16;

  bf16x8 qf[8];   // Q-hoist: B-frags, col=q16, k contiguous
  {
    const char* base = (const char*)(wq + ((size_t)b*NQ + q0w + q16)*D);
    #pragma unroll
    for (int ks=0;ks<8;ks++) qf[ks] = as_bf(*(const u32x4*)(base + ks*64 + g*16));
  }

  f32x4 z4 = {0.f,0.f,0.f,0.f};
  f32x4 o[32];
  #pragma unroll
  for (int i=0;i<32;i++) o[i]=z4;
  float ssum = 0.f;

  const char* wk_b  = (const char*)(wk  + (size_t)b*NK*D);
  const char* wvt_b = (const char*)(wvt + (size_t)b*FV*NK);
  const float c1 = 0.0625f * 1.44269504088896f;   // temp*log2(e)

  for (int kv0 = 0; kv0 < NK; kv0 += 32){
    { // stage K tile [32][256]bf16 (contiguous 16KB) with pre-swizzled source
      const char* src0 = wk_b + (size_t)kv0*D*2;
      #pragma unroll
      for (int it=0; it<4; it++){
        int dd = wid*4096 + it*1024 + lane*16;
        int so = dd ^ (((dd>>9)&7)<<4);           // rows 512B: XOR bits4-6<-bits9-11
        gload16(src0 + so, wk_lds + wid*4096 + it*1024);
      }
      // stage V^T tile [512][32]bf16 (gather 64B row-chunks), pre-swizzled
      #pragma unroll
      for (int it=0; it<8; it++){
        int dd = wid*8192 + it*1024 + lane*16;
        int ds_ = dd ^ (((dd>>6)&3)<<4);          // rows 64B: XOR bits4-5<-bits6-7
        int vrow = ds_ >> 6;
        int cb = ds_ & 63;
        gload16(wvt_b + (size_t)vrow*(NK*2) + (size_t)kv0*2 + cb,
                wv_lds + wid*8192 + it*1024);
      }
    }
    __syncthreads();

    // QK^T -> S^T[kv][q], kv=4g+r+16mi, q=q16
    f32x4 sc[2]; sc[0]=z4; sc[1]=z4;
    #pragma unroll
    for (int ks=0;ks<8;ks++){
      #pragma unroll
      for (int mi=0;mi<2;mi++){
        int row = mi*16 + q16;
        int lin = row*512 + ks*64 + g*16;
        bf16x8 a = as_bf(*(const u32x4*)(wk_lds + (lin ^ ((row&7)<<4))));
        sc[mi] = __builtin_amdgcn_mfma_f32_16x16x32_bf16(a, qf[ks], sc[mi], 0,0,0);
      }
    }
    // fixed-max softmax numerator + running denominator
    float ps[2][4];
    float part = 0.f;
    #pragma unroll
    for (int mi=0;mi<2;mi++){
      #pragma unroll
      for (int r=0;r<4;r++){
        float p = exp2f((sc[mi][r]-1.0f)*c1);
        ps[mi][r]=p; part += p;
      }
    }
    part += __shfl_xor(part,16);
    part += __shfl_xor(part,32);
    ssum += part;
    // P C/D-layout -> A/B-frag layout via 1KB/wave LDS bounce (swizzled)
    {
      char* pw = p_lds + wid*1024;
      #pragma unroll
      for (int mi=0;mi<2;mi++){
        #pragma unroll
        for (int rp=0;rp<2;rp++){
          unsigned u = pack2(ps[mi][2*rp], ps[mi][2*rp+1]);
          int addr = q16*64 + mi*32 + g*8 + rp*4;
          *(unsigned*)(pw + (addr ^ ((q16&3)<<4))) = u;
        }
      }
    }
    bf16x8 pb;
    {
      int addr = q16*64 + g*16;
      pb = as_bf(*(const u32x4*)(p_lds + wid*1024 + (addr ^ ((q16&3)<<4))));
    }
    // O^T += Vt . P^T   (pb reused across all 32 v-frags)
    #pragma unroll
    for (int ai=0;ai<32;ai++){
      int vrow = ai*16 + q16;
      int lin = vrow*64 + g*16;
      bf16x8 a = as_bf(*(const u32x4*)(wv_lds + (lin ^ ((vrow&3)<<4))));
      o[ai] = __builtin_amdgcn_mfma_f32_16x16x32_bf16(a, pb, o[ai], 0,0,0);
    }
    __syncthreads();
  }

  // epilogue: O^T/s -> transpose via LDS -> +query -> coalesced f32 stores
  float inv = 1.f/ssum;
  {
    char* eo = smem + wid*8192;    // 8KB/wave, reuses staging LDS (post-barrier)
    const size_t rowbase = (size_t)b*NQ + q0w;
    const int qr = lane >> 2;
    const int xo = (lane & 3) * 32;
    #pragma unroll
    for (int c=0;c<4;c++){
      #pragma unroll
      for (int i=0;i<8;i++){
        int ai = c*8+i;
        f32x4 v;
        #pragma unroll
        for (int r=0;r<4;r++) v[r] = o[ai][r]*inv;
        int byte = q16*512 + (i*16 + g*4)*4;
        *(f32x4*)(eo + (byte ^ ((q16&7)<<4))) = v;
      }
      #pragma unroll
      for (int i=0;i<8;i++){
        int off = xo + i*4;
        int byte = qr*512 + off*4;
        f32x4 v = *(const f32x4*)(eo + (byte ^ ((qr&7)<<4)));
        const float* qp = query + (rowbase + qr)*F + c*128 + off;
        f32x4 qv = *(const f32x4*)qp;
        #pragma unroll
        for (int r=0;r<4;r++) v[r] += qv[r];
        *(f32x4*)(out + (rowbase + qr)*F + c*128 + off) = v;
      }
    }
  }
}

extern "C" void kernel_launch(void* const* d_in, const int* in_sizes, int n_in,
                              void* d_out, int out_size, void* d_ws, size_t ws_size,
                              hipStream_t stream)
{
  const float* query = (const float*)d_in[0];
  const float* key   = (const float*)d_in[1];
  const float* value = (const float*)d_in[2];
  const float* WQ    = (const float*)d_in[3];
  const float* WK    = (const float*)d_in[4];
  const float* WV    = (const float*)d_in[5];
  float* out = (float*)d_out;

  unsigned short* wq  = (unsigned short*)d_ws;              // [B*NQ][256] bf16, 16MB
  unsigned short* wk  = wq + (size_t)BB*NQ*D;               // [B*NK][256] bf16, 16MB
  unsigned short* wvt = wk + (size_t)BB*NK*D;               // [B][512][NK] bf16, 32MB

  dim3 blk(256);
  proj_kernel<512,256,false><<<1024, blk, 0, stream>>>(query, WQ, wq);
  proj_kernel<256,256,false><<<1024, blk, 0, stream>>>(key,   WK, wk);
  proj_kernel<256,512,true ><<<1024, blk, 0, stream>>>(value, WV, wvt);
  attn_kernel<<<512, blk, 0, stream>>>(query, wq, wk, wvt, out);
}

// Round 2
// 249.438 us; speedup vs baseline: 1.3577x; 1.3577x over previous
//
#include <hip/hip_runtime.h>

typedef float        f32x4  __attribute__((ext_vector_type(4)));
typedef unsigned int u32x4  __attribute__((ext_vector_type(4)));
typedef unsigned int u32x2  __attribute__((ext_vector_type(2)));
typedef __bf16       bf16x8 __attribute__((ext_vector_type(8)));

#define DEVFN static __device__ __forceinline__

DEVFN unsigned short f2bf(float f){
  unsigned u = __builtin_bit_cast(unsigned, f);
  u += 0x7FFFu + ((u >> 16) & 1u);            // RNE
  return (unsigned short)(u >> 16);
}
DEVFN unsigned cvtpk(float a, float b){       // dst.lo=bf16(a), dst.hi=bf16(b)
  unsigned r;
  asm("v_cvt_pk_bf16_f32 %0, %1, %2" : "=v"(r) : "v"(a), "v"(b));
  return r;
}
DEVFN bf16x8 as_bf(u32x4 v){ union{u32x4 u; bf16x8 b;} x; x.u=v; return x.b; }

DEVFN void gload16(const char* src, char* lds){
  __builtin_amdgcn_global_load_lds(
      (__attribute__((address_space(1))) void*)src,
      (__attribute__((address_space(3))) void*)lds, 16, 0, 0);
}

constexpr int BB = 16, NQ = 2048, NK = 2048, F = 512, D = 256, FV = 512;

// ---------------- projection + row l2norm ----------------
// Y[m][n] = l2norm_rows( X[m][:] . W[n][:] ), 32 rows/block.
// TR=true: write Y transposed per-batch: Yt[b][n][m%2048].
template<int KD, int ND, bool TR>
__global__ __launch_bounds__(256,2) void proj_kernel(const float* __restrict__ X,
                                                     const float* __restrict__ W,
                                                     unsigned short* __restrict__ Y)
{
  constexpr int NW = ND/4;
  constexpr int AF = TR ? 8 : 2;
  constexpr int BF = TR ? 2 : NW/16;
  __shared__ __align__(16) char xsm[32*80];
  __shared__ __align__(16) char wsm[ND*80];
  __shared__ float wsum[4][32];
  const int tid = threadIdx.x;
  const int lane = tid & 63;
  const int wid = tid >> 6;
  const int q16 = lane & 15;
  const int g = lane >> 4;
  const int row0 = blockIdx.x * 32;
  const int rX = tid >> 3, cX = (tid & 7) * 4;

  f32x4 z4 = {0.f,0.f,0.f,0.f};
  f32x4 acc[AF][BF];
  #pragma unroll
  for (int i=0;i<AF;i++){
    #pragma unroll
    for (int j=0;j<BF;j++) acc[i][j] = z4;
  }

  for (int k0 = 0; k0 < KD; k0 += 32){
    { // X tile [32][32] -> bf16 LDS, stride 80B (pad kills conflicts)
      f32x4 v = *(const f32x4*)(X + (size_t)(row0+rX)*KD + k0 + cX);
      u32x2 p; p[0]=cvtpk(v[0],v[1]); p[1]=cvtpk(v[2],v[3]);
      *(u32x2*)(xsm + rX*80 + cX*2) = p;
    }
    #pragma unroll
    for (int j=0;j<ND/32;j++){ // W tile [ND][32]
      int r = j*32 + rX;
      f32x4 v = *(const f32x4*)(W + (size_t)r*KD + k0 + cX);
      u32x2 p; p[0]=cvtpk(v[0],v[1]); p[1]=cvtpk(v[2],v[3]);
      *(u32x2*)(wsm + r*80 + cX*2) = p;
    }
    __syncthreads();
    if constexpr (!TR){
      bf16x8 a[2], bb[BF];
      #pragma unroll
      for (int mi=0;mi<2;mi++)  a[mi]  = as_bf(*(const u32x4*)(xsm + (16*mi+q16)*80 + g*16));
      #pragma unroll
      for (int ni=0;ni<BF;ni++) bb[ni] = as_bf(*(const u32x4*)(wsm + (wid*NW + 16*ni + q16)*80 + g*16));
      #pragma unroll
      for (int mi=0;mi<2;mi++){
        #pragma unroll
        for (int ni=0;ni<BF;ni++)
          acc[mi][ni] = __builtin_amdgcn_mfma_f32_16x16x32_bf16(a[mi], bb[ni], acc[mi][ni], 0,0,0);
      }
    } else {
      bf16x8 a[8], bb[2];
      #pragma unroll
      for (int ai=0;ai<8;ai++) a[ai] = as_bf(*(const u32x4*)(wsm + (wid*NW + 16*ai + q16)*80 + g*16));
      #pragma unroll
      for (int ci=0;ci<2;ci++) bb[ci] = as_bf(*(const u32x4*)(xsm + (16*ci+q16)*80 + g*16));
      #pragma unroll
      for (int ai=0;ai<8;ai++){
        #pragma unroll
        for (int ci=0;ci<2;ci++)
          acc[ai][ci] = __builtin_amdgcn_mfma_f32_16x16x32_bf16(a[ai], bb[ci], acc[ai][ci], 0,0,0);
      }
    }
    __syncthreads();
  }

  if constexpr (!TR){
    float part[2][4];
    #pragma unroll
    for (int mi=0;mi<2;mi++){
      #pragma unroll
      for (int r=0;r<4;r++){
        float s=0.f;
        #pragma unroll
        for (int ni=0;ni<BF;ni++){ float v=acc[mi][ni][r]; s += v*v; }
        part[mi][r]=s;
      }
    }
    #pragma unroll
    for (int m=1;m<16;m<<=1){
      #pragma unroll
      for (int mi=0;mi<2;mi++){
        #pragma unroll
        for (int r=0;r<4;r++) part[mi][r] += __shfl_xor(part[mi][r], m);
      }
    }
    if (q16 == 0){
      #pragma unroll
      for (int mi=0;mi<2;mi++){
        #pragma unroll
        for (int r=0;r<4;r++) wsum[wid][16*mi + 4*g + r] = part[mi][r];
      }
    }
    __syncthreads();
    #pragma unroll
    for (int mi=0;mi<2;mi++){
      #pragma unroll
      for (int r=0;r<4;r++){
        int m = 16*mi + 4*g + r;
        float tot = wsum[0][m]+wsum[1][m]+wsum[2][m]+wsum[3][m];
        float inv = 1.f / fmaxf(sqrtf(tot), 1e-12f);
        #pragma unroll
        for (int ni=0;ni<BF;ni++){
          int col = wid*NW + 16*ni + q16;
          Y[(size_t)(row0+m)*ND + col] = f2bf(acc[mi][ni][r]*inv);
        }
      }
    }
  } else {
    float pp[2];
    #pragma unroll
    for (int ci=0;ci<2;ci++){
      float s=0.f;
      #pragma unroll
      for (int ai=0;ai<8;ai++){
        #pragma unroll
        for (int r=0;r<4;r++){ float v=acc[ai][ci][r]; s += v*v; }
      }
      pp[ci]=s;
    }
    #pragma unroll
    for (int ci=0;ci<2;ci++){
      pp[ci] += __shfl_xor(pp[ci],16);
      pp[ci] += __shfl_xor(pp[ci],32);
    }
    if (lane < 16){ wsum[wid][lane] = pp[0]; wsum[wid][16+lane] = pp[1]; }
    __syncthreads();
    #pragma unroll
    for (int ci=0;ci<2;ci++){
      int m = 16*ci + q16;
      float tot = wsum[0][m]+wsum[1][m]+wsum[2][m]+wsum[3][m];
      float inv = 1.f / fmaxf(sqrtf(tot), 1e-12f);
      int grow = row0 + m;
      int b = grow >> 11;
      int kv = grow & 2047;
      #pragma unroll
      for (int ai=0;ai<8;ai++){
        #pragma unroll
        for (int r=0;r<4;r++){
          int n = wid*NW + 16*ai + 4*g + r;
          Y[((size_t)b*FV + n)*NK + kv] = f2bf(acc[ai][ci][r]*inv);
        }
      }
    }
  }
}

// ---------------- fused attention ----------------
// 256 blocks (16 batch x 16 qblk), 512 threads = 8 waves x 16 q-rows.
// kv tiles of 32, double-buffered fragment-major LDS, 1 barrier per tile.
// S^T = mfma(K, Q); fixed softmax max (cosine logits <= 1/16); O^T = mfma(Vt, P^T).
__global__ __launch_bounds__(512,2) void attn_kernel(const float* __restrict__ query,
    const unsigned short* __restrict__ wq, const unsigned short* __restrict__ wk,
    const unsigned short* __restrict__ wvt, float* __restrict__ out)
{
  // LDS map: K dbuf 2x16K @0 | V dbuf 2x32K @32768 | P 8x1K @98304
  __shared__ __align__(16) char smem[106496];
  const int tid = threadIdx.x, lane = tid & 63, wid = tid >> 6;
  const int q16 = lane & 15, g = lane >> 4;
  const int bid = blockIdx.x;
  const int lb = (bid & 7)*32 + (bid >> 3);     // XCD-chunk swizzle (256=8*32, bijective)
  const int b = lb >> 4;
  const int qblk = lb & 15;
  const int q0w = qblk*128 + wid*16;

  const int lrow = lane >> 2;                   // staging source row within 16
  const int lcol = (lane & 3) * 16;             // staging source 16B chunk
  const int rc16 = ((lane & 15)*4 + (lane >> 4))*16;  // frag read chunk (conflict-free)

  const char* wk_b  = (const char*)(wk  + (size_t)b*NK*D);
  const char* wvt_b = (const char*)(wvt + (size_t)b*FV*NK);

  // per-wave staging source bases (lane-resolved); add kv0 term per tile
  const char* ksrcA = wk_b + (size_t)(lrow      )*512 + wid*64 + lcol;  // j=2w   (mi=0,ks=w)
  const char* ksrcB = wk_b + (size_t)(16 + lrow )*512 + wid*64 + lcol;  // j=2w+1 (mi=1,ks=w)
  const char* vsrc0 = wvt_b + (size_t)((wid*4+0)*16 + lrow)*4096 + lcol;
  const char* vsrc1 = wvt_b + (size_t)((wid*4+1)*16 + lrow)*4096 + lcol;
  const char* vsrc2 = wvt_b + (size_t)((wid*4+2)*16 + lrow)*4096 + lcol;
  const char* vsrc3 = wvt_b + (size_t)((wid*4+3)*16 + lrow)*4096 + lcol;

  #define STAGE(KV0, CUR) do{                                              \
    char* kb_ = smem + (CUR)*16384;                                        \
    char* vb_ = smem + 32768 + (CUR)*32768;                                \
    size_t ko_ = (size_t)(KV0)*512, vo_ = (size_t)(KV0)*2;                 \
    gload16(ksrcA + ko_, kb_ + (wid*2  )*1024);                            \
    gload16(ksrcB + ko_, kb_ + (wid*2+1)*1024);                            \
    gload16(vsrc0 + vo_, vb_ + (wid*4+0)*1024);                            \
    gload16(vsrc1 + vo_, vb_ + (wid*4+1)*1024);                            \
    gload16(vsrc2 + vo_, vb_ + (wid*4+2)*1024);                            \
    gload16(vsrc3 + vo_, vb_ + (wid*4+3)*1024);                            \
  }while(0)

  STAGE(0, 0);

  bf16x8 qf[8];   // Q-hoist: B-frags, col=q16, k contiguous
  {
    const char* base = (const char*)(wq + ((size_t)b*NQ + q0w + q16)*D);
    #pragma unroll
    for (int ks=0;ks<8;ks++) qf[ks] = as_bf(*(const u32x4*)(base + ks*64 + g*16));
  }

  f32x4 z4 = {0.f,0.f,0.f,0.f};
  f32x4 o[32];
  #pragma unroll
  for (int i=0;i<32;i++) o[i]=z4;
  float ssum = 0.f;
  const float c1 = 0.0625f * 1.44269504088896f;   // temp*log2(e)
  char* const pw = smem + 98304 + wid*1024;

  __syncthreads();

  for (int t = 0; t < 64; ++t){
    const int cur = t & 1;
    if (t < 63) STAGE((t+1)*32, cur^1);           // prefetch next tile into other buffer
    const char* kb = smem + cur*16384;
    const char* vb = smem + 32768 + cur*32768;

    // QK^T -> S^T[kv][q], kv=4g+r+16mi, q=q16
    f32x4 sc[2]; sc[0]=z4; sc[1]=z4;
    #pragma unroll
    for (int ks=0;ks<8;ks++){
      #pragma unroll
      for (int mi=0;mi<2;mi++){
        bf16x8 a = as_bf(*(const u32x4*)(kb + (ks*2+mi)*1024 + rc16));
        sc[mi] = __builtin_amdgcn_mfma_f32_16x16x32_bf16(a, qf[ks], sc[mi], 0,0,0);
      }
    }
    // fixed-max softmax numerator + running denominator
    float ps[2][4];
    float part = 0.f;
    #pragma unroll
    for (int mi=0;mi<2;mi++){
      #pragma unroll
      for (int r=0;r<4;r++){
        float p = exp2f((sc[mi][r]-1.0f)*c1);
        ps[mi][r]=p; part += p;
      }
    }
    part += __shfl_xor(part,16);
    part += __shfl_xor(part,32);
    ssum += part;
    // P C/D-layout -> B-frag layout via 1KB/wave LDS bounce
    #pragma unroll
    for (int mi=0;mi<2;mi++){
      #pragma unroll
      for (int rp=0;rp<2;rp++){
        unsigned u = cvtpk(ps[mi][2*rp], ps[mi][2*rp+1]);
        int addr = q16*64 + mi*32 + g*8 + rp*4;
        *(unsigned*)(pw + (addr ^ ((q16&3)<<4))) = u;
      }
    }
    bf16x8 pb;
    {
      int addr = q16*64 + g*16;
      pb = as_bf(*(const u32x4*)(pw + (addr ^ ((q16&3)<<4))));
    }
    // O^T += Vt . P^T   (pb reused across all 32 v-frags)
    #pragma unroll
    for (int ai=0;ai<32;ai++){
      bf16x8 a = as_bf(*(const u32x4*)(vb + ai*1024 + rc16));
      o[ai] = __builtin_amdgcn_mfma_f32_16x16x32_bf16(a, pb, o[ai], 0,0,0);
    }
    __syncthreads();   // drains this wave's prefetch (vmcnt 0) + tile handoff
  }
  #undef STAGE

  // epilogue: O^T/s -> transpose via LDS -> +query -> coalesced f32 stores
  float inv = 1.f/ssum;
  {
    char* eo = smem + wid*8192;    // 8KB/wave, reuses staging LDS (post-barrier)
    const size_t rowbase = (size_t)b*NQ + q0w;
    const int qr = lane >> 2;
    const int xo = (lane & 3) * 32;
    #pragma unroll
    for (int c=0;c<4;c++){
      #pragma unroll
      for (int i=0;i<8;i++){
        int ai = c*8+i;
        f32x4 v;
        #pragma unroll
        for (int r=0;r<4;r++) v[r] = o[ai][r]*inv;
        int byte = q16*512 + (i*16 + g*4)*4;
        *(f32x4*)(eo + (byte ^ ((q16&7)<<4))) = v;
      }
      #pragma unroll
      for (int i=0;i<8;i++){
        int off = xo + i*4;
        int byte = qr*512 + off*4;
        f32x4 v = *(const f32x4*)(eo + (byte ^ ((qr&7)<<4)));
        const float* qp = query + (rowbase + qr)*F + c*128 + off;
        f32x4 qv = *(const f32x4*)qp;
        #pragma unroll
        for (int r=0;r<4;r++) v[r] += qv[r];
        *(f32x4*)(out + (rowbase + qr)*F + c*128 + off) = v;
      }
    }
  }
}

extern "C" void kernel_launch(void* const* d_in, const int* in_sizes, int n_in,
                              void* d_out, int out_size, void* d_ws, size_t ws_size,
                              hipStream_t stream)
{
  const float* query = (const float*)d_in[0];
  const float* key   = (const float*)d_in[1];
  const float* value = (const float*)d_in[2];
  const float* WQ    = (const float*)d_in[3];
  const float* WK    = (const float*)d_in[4];
  const float* WV    = (const float*)d_in[5];
  float* out = (float*)d_out;

  unsigned short* wq  = (unsigned short*)d_ws;              // [B*NQ][256] bf16, 16MB
  unsigned short* wk  = wq + (size_t)BB*NQ*D;               // [B*NK][256] bf16, 16MB
  unsigned short* wvt = wk + (size_t)BB*NK*D;               // [B][512][NK] bf16, 32MB

  dim3 blk(256);
  proj_kernel<512,256,false><<<1024, blk, 0, stream>>>(query, WQ, wq);
  proj_kernel<256,256,false><<<1024, blk, 0, stream>>>(key,   WK, wk);
  proj_kernel<256,512,true ><<<1024, blk, 0, stream>>>(value, WV, wvt);
  attn_kernel<<<256, dim3(512), 0, stream>>>(query, wq, wk, wvt, out);
}